// Round 2
// baseline (835.361 us; speedup 1.0000x reference)
//
#include <hip/hip_runtime.h>

#define N_NODES 16000
#define NODES_G 2000
#define BATCH 8
#define INF 128
#define HCDIM 128
#define E_IN 512000
#define E_SL 528000
#define MAXDEG_LDS 64
#define MAXDEG 256
#define NEG_SLOPE 0.2f
#define LN_EPS 1e-5f
#define MS_DIM 6000
#define FC1_DIM 512
#define FC2_DIM 128

__global__ __launch_bounds__(256) void zero_cnt_kernel(int* cnt) {
    int i = blockIdx.x * 256 + threadIdx.x;
    if (i < N_NODES) cnt[i] = 0;
}

__global__ __launch_bounds__(256) void hist_kernel(const int* __restrict__ ei, int* __restrict__ cnt) {
    int e = blockIdx.x * 256 + threadIdx.x;
    if (e >= E_SL) return;
    int d = (e < E_IN) ? ei[E_IN + e] : (e - E_IN);
    atomicAdd(&cnt[d], 1);
}

__global__ __launch_bounds__(1024) void scan_kernel(const int* __restrict__ cnt,
                                                    int* __restrict__ rowS, int* __restrict__ rowN) {
    __shared__ int part[1024];
    int t = threadIdx.x;
    int base = t * 16;
    int local[16];
    int s = 0;
    if (base < N_NODES) {
        #pragma unroll
        for (int k = 0; k < 16; ++k) { local[k] = cnt[base + k]; s += local[k]; }
    }
    part[t] = s;
    __syncthreads();
    for (int off = 1; off < 1024; off <<= 1) {
        int v = part[t];
        int add = (t >= off) ? part[t - off] : 0;
        __syncthreads();
        part[t] = v + add;
        __syncthreads();
    }
    int excl = (t == 0) ? 0 : part[t - 1];
    if (base < N_NODES) {
        int run = excl;
        #pragma unroll
        for (int k = 0; k < 16; ++k) {
            rowS[base + k] = run;
            rowN[base + k] = run;
            run += local[k];
        }
        if (base + 16 == N_NODES) rowS[N_NODES] = run;
    }
}

__global__ __launch_bounds__(256) void scatter_kernel(const int* __restrict__ ei,
                                                      int* __restrict__ rowN, int* __restrict__ csrc) {
    int e = blockIdx.x * 256 + threadIdx.x;
    if (e >= E_SL) return;
    int s, d;
    if (e < E_IN) { s = ei[e]; d = ei[E_IN + e]; }
    else { s = e - E_IN; d = s; }
    int pos = atomicAdd(&rowN[d], 1);
    csrc[pos] = s;
}

// x0 = mean over 128 features; one wave per node
__global__ __launch_bounds__(256) void x0_kernel(const float* __restrict__ x, float* __restrict__ ms) {
    int wid = (blockIdx.x * 256 + threadIdx.x) >> 6;   // node id (grid exact)
    int lane = threadIdx.x & 63;
    float v = x[wid * INF + lane] + x[wid * INF + 64 + lane];
    #pragma unroll
    for (int off = 32; off > 0; off >>= 1) v += __shfl_xor(v, off, 64);
    if (lane == 0) {
        int b = wid / NODES_G, i = wid % NODES_G;
        ms[b * MS_DIM + i] = v * (1.0f / INF);
    }
}

// out1 = X@W1^T + b1 ; out2 = X@W2^T + b2 ; X:[N,128], W:[128,128]
__global__ __launch_bounds__(256) void gemm_dual_kernel(
    const float* __restrict__ X,
    const float* __restrict__ W1, const float* __restrict__ b1,
    const float* __restrict__ W2, const float* __restrict__ b2,
    float* __restrict__ out1, float* __restrict__ out2) {
    __shared__ float xs[32 * 128];
    int t = threadIdx.x;
    int row0 = blockIdx.x * 32;
    const float4* src = reinterpret_cast<const float4*>(X + (size_t)row0 * HCDIM);
    float4* dst = reinterpret_cast<float4*>(xs);
    #pragma unroll
    for (int i = 0; i < 4; ++i) dst[t + i * 256] = src[t + i * 256];
    __syncthreads();
    int col = t & 127;
    int half = t >> 7;
    const float* W = half ? W2 : W1;
    float bv = (half ? b2 : b1)[col];
    float* outp = half ? out2 : out1;
    float acc[32];
    #pragma unroll
    for (int r = 0; r < 32; ++r) acc[r] = 0.f;
    for (int k0 = 0; k0 < 128; k0 += 4) {
        float4 w4 = *reinterpret_cast<const float4*>(W + col * HCDIM + k0);
        #pragma unroll
        for (int r = 0; r < 32; ++r) {
            acc[r] += xs[r * 128 + k0] * w4.x + xs[r * 128 + k0 + 1] * w4.y
                    + xs[r * 128 + k0 + 2] * w4.z + xs[r * 128 + k0 + 3] * w4.w;
        }
    }
    #pragma unroll
    for (int r = 0; r < 32; ++r) outp[(size_t)(row0 + r) * HCDIM + col] = acc[r] + bv;
}

// Fused GATv2 per-destination-node: logits + segment softmax + aggregate + bias + relu + pooling
__global__ __launch_bounds__(128) void gat_node_kernel(
    const float* __restrict__ xl, const float* __restrict__ xr,
    const int* __restrict__ rowS, const int* __restrict__ csrc,
    const float* __restrict__ att, const float* __restrict__ bias,
    const float* __restrict__ Wp, const float* __restrict__ bp,
    float* __restrict__ hout, float* __restrict__ msout) {
    int n = blockIdx.x;
    int ch = threadIdx.x;
    int h = ch >> 5;
    __shared__ float xls[MAXDEG_LDS][HCDIM];
    __shared__ float as_[MAXDEG][5];     // [j][h], padded to kill bank conflicts
    __shared__ float wred[2];
    float xrv = xr[(size_t)n * HCDIM + ch];
    float attv = att[ch];
    int rs = rowS[n], re = rowS[n + 1];
    int deg = re - rs;
    int degc = deg < MAXDEG ? deg : MAXDEG;

    for (int j = 0; j < degc; ++j) {
        int src = csrc[rs + j];
        float v = xl[(size_t)src * HCDIM + ch];
        if (j < MAXDEG_LDS) xls[j][ch] = v;
        float tt = v + xrv;
        tt = tt > 0.f ? tt : NEG_SLOPE * tt;
        float p = tt * attv;
        #pragma unroll
        for (int o = 16; o > 0; o >>= 1) p += __shfl_xor(p, o, 32);
        if ((ch & 31) == 0) as_[j][h] = p;
    }
    __syncthreads();

    // per-head softmax stats: 32 threads per head (half-wave aligned)
    int s = ch & 31;
    float m = -1e30f;
    for (int j = s; j < degc; j += 32) m = fmaxf(m, as_[j][h]);
    #pragma unroll
    for (int o = 16; o > 0; o >>= 1) m = fmaxf(m, __shfl_xor(m, o, 32));
    float dsum = 0.f;
    for (int j = s; j < degc; j += 32) {
        float e = __expf(as_[j][h] - m);
        as_[j][h] = e;
        dsum += e;
    }
    #pragma unroll
    for (int o = 16; o > 0; o >>= 1) dsum += __shfl_xor(dsum, o, 32);
    __syncthreads();

    float rden = 1.0f / dsum;
    float acc = 0.f;
    for (int j = 0; j < degc; ++j) {
        float w = as_[j][h] * rden;
        float v = (j < MAXDEG_LDS) ? xls[j][ch] : xl[(size_t)csrc[rs + j] * HCDIM + ch];
        acc += w * v;
    }
    float o = acc + bias[ch];
    o = fmaxf(o, 0.f);
    hout[(size_t)n * HCDIM + ch] = o;

    // fused pooling: ms_slot[n] = sum_ch o*Wp[ch] + bp
    float p = o * Wp[ch];
    #pragma unroll
    for (int off = 32; off > 0; off >>= 1) p += __shfl_xor(p, off, 64);
    if ((ch & 63) == 0) wred[ch >> 6] = p;
    __syncthreads();
    if (ch == 0) {
        int b = n / NODES_G, i = n % NODES_G;
        msout[b * MS_DIM + i] = wred[0] + wred[1] + bp[0];
    }
}

// LayerNorm in place over rows of 2000 within ms; 24 blocks
__global__ __launch_bounds__(256) void ln_kernel(float* __restrict__ ms,
                                                 const float* __restrict__ g, const float* __restrict__ bta) {
    int b = blockIdx.x / 3, st = blockIdx.x % 3;
    float* row = ms + b * MS_DIM + st * NODES_G;
    int t = threadIdx.x;
    float s = 0.f, ss = 0.f;
    for (int j = t; j < NODES_G; j += 256) { float v = row[j]; s += v; ss += v * v; }
    __shared__ float rs_[4], rss[4];
    #pragma unroll
    for (int off = 32; off > 0; off >>= 1) { s += __shfl_xor(s, off, 64); ss += __shfl_xor(ss, off, 64); }
    int w = t >> 6, lane = t & 63;
    if (lane == 0) { rs_[w] = s; rss[w] = ss; }
    __syncthreads();
    s = rs_[0] + rs_[1] + rs_[2] + rs_[3];
    ss = rss[0] + rss[1] + rss[2] + rss[3];
    float mean = s * (1.0f / NODES_G);
    float var = ss * (1.0f / NODES_G) - mean * mean;
    float rstd = rsqrtf(var + LN_EPS);
    for (int j = t; j < NODES_G; j += 256) {
        float v = row[j];
        row[j] = (v - mean) * rstd * g[j] + bta[j];
    }
}

// z[b][o] = act(sum_k in[b][k]*W[o][k] + bias[o]); one wave per o, 8 batch accs
template<int K, int OD, bool RELU>
__global__ __launch_bounds__(256) void fc_kernel(const float* __restrict__ in, const float* __restrict__ W,
                                                 const float* __restrict__ bias, float* __restrict__ z) {
    int lane = threadIdx.x & 63;
    int o = blockIdx.x * 4 + (threadIdx.x >> 6);
    float acc[8];
    #pragma unroll
    for (int b = 0; b < 8; ++b) acc[b] = 0.f;
    for (int k = lane; k < K; k += 64) {
        float wv = W[(size_t)o * K + k];
        #pragma unroll
        for (int b = 0; b < 8; ++b) acc[b] += wv * in[b * K + k];
    }
    #pragma unroll
    for (int off = 32; off > 0; off >>= 1)
        #pragma unroll
        for (int b = 0; b < 8; ++b) acc[b] += __shfl_xor(acc[b], off, 64);
    if (lane == 0) {
        float bb = bias[o];
        #pragma unroll
        for (int b = 0; b < 8; ++b) {
            float v = acc[b] + bb;
            z[b * OD + o] = RELU ? fmaxf(v, 0.f) : v;
        }
    }
}

__global__ __launch_bounds__(256) void fc3_kernel(const float* __restrict__ z2, const float* __restrict__ W,
                                                  const float* __restrict__ bias, float* __restrict__ out) {
    int t = threadIdx.x;
    int b = t >> 5, l = t & 31;
    float acc = 0.f;
    #pragma unroll
    for (int i = 0; i < 4; ++i) {
        int k = l + i * 32;
        acc += z2[b * FC2_DIM + k] * W[k];
    }
    #pragma unroll
    for (int off = 16; off > 0; off >>= 1) acc += __shfl_xor(acc, off, 32);
    if (l == 0) out[b] = acc + bias[0];
}

extern "C" void kernel_launch(void* const* d_in, const int* in_sizes, int n_in,
                              void* d_out, int out_size, void* d_ws, size_t ws_size,
                              hipStream_t stream) {
    const float* x    = (const float*)d_in[0];
    const int*   ei   = (const int*)d_in[1];
    const float* Wl1  = (const float*)d_in[2];
    const float* bl1  = (const float*)d_in[3];
    const float* Wr1  = (const float*)d_in[4];
    const float* br1  = (const float*)d_in[5];
    const float* att1 = (const float*)d_in[6];
    const float* bias1= (const float*)d_in[7];
    const float* Wl2  = (const float*)d_in[8];
    const float* bl2  = (const float*)d_in[9];
    const float* Wr2  = (const float*)d_in[10];
    const float* br2  = (const float*)d_in[11];
    const float* att2 = (const float*)d_in[12];
    const float* bias2= (const float*)d_in[13];
    const float* Wp1  = (const float*)d_in[14];
    const float* bp1  = (const float*)d_in[15];
    const float* Wp2  = (const float*)d_in[16];
    const float* bp2  = (const float*)d_in[17];
    const float* ln_g = (const float*)d_in[18];
    const float* ln_b = (const float*)d_in[19];
    const float* We1  = (const float*)d_in[20];
    const float* be1  = (const float*)d_in[21];
    const float* We2  = (const float*)d_in[22];
    const float* be2  = (const float*)d_in[23];
    const float* We3  = (const float*)d_in[24];
    const float* be3  = (const float*)d_in[25];
    float* out = (float*)d_out;

    float* ws = (float*)d_ws;
    float* xl = ws;
    float* xr = xl + (size_t)N_NODES * HCDIM;   // 2,048,000
    float* hb = xr + (size_t)N_NODES * HCDIM;
    float* ms = hb + (size_t)N_NODES * HCDIM;
    float* z1 = ms + BATCH * MS_DIM;            // 48,000
    float* z2 = z1 + BATCH * FC1_DIM;
    int* cnt  = (int*)(z2 + BATCH * FC2_DIM);
    int* rowS = cnt + N_NODES;
    int* rowN = rowS + (N_NODES + 1);
    int* csrc = rowN + N_NODES;

    int eb = (E_SL + 255) / 256;
    zero_cnt_kernel<<<(N_NODES + 255) / 256, 256, 0, stream>>>(cnt);
    hist_kernel<<<eb, 256, 0, stream>>>(ei, cnt);
    scan_kernel<<<1, 1024, 0, stream>>>(cnt, rowS, rowN);
    scatter_kernel<<<eb, 256, 0, stream>>>(ei, rowN, csrc);
    x0_kernel<<<N_NODES / 4, 256, 0, stream>>>(x, ms);

    gemm_dual_kernel<<<N_NODES / 32, 256, 0, stream>>>(x, Wl1, bl1, Wr1, br1, xl, xr);
    gat_node_kernel<<<N_NODES, 128, 0, stream>>>(xl, xr, rowS, csrc, att1, bias1, Wp1, bp1, hb, ms + 2000);
    gemm_dual_kernel<<<N_NODES / 32, 256, 0, stream>>>(hb, Wl2, bl2, Wr2, br2, xl, xr);
    gat_node_kernel<<<N_NODES, 128, 0, stream>>>(xl, xr, rowS, csrc, att2, bias2, Wp2, bp2, hb, ms + 4000);

    ln_kernel<<<24, 256, 0, stream>>>(ms, ln_g, ln_b);
    fc_kernel<MS_DIM, FC1_DIM, true><<<FC1_DIM / 4, 256, 0, stream>>>(ms, We1, be1, z1);
    fc_kernel<FC1_DIM, FC2_DIM, true><<<FC2_DIM / 4, 256, 0, stream>>>(z1, We2, be2, z2);
    fc3_kernel<<<1, 256, 0, stream>>>(z2, We3, be3, out);
}

// Round 5
// 405.984 us; speedup vs baseline: 2.0576x; 2.0576x over previous
//
#include <hip/hip_runtime.h>

#define N_NODES 16000
#define NODES_G 2000
#define BATCH 8
#define INF 128
#define HCDIM 128
#define E_IN 512000
#define E_SL 528000
#define LMAX 128          // max degree handled fully in LDS logits (observed max ~57)
#define LSTRIDE 132       // padded stride for as_ to avoid bank conflicts
#define NEG_SLOPE 0.2f
#define LN_EPS 1e-5f
#define MS_DIM 6000
#define FC1_DIM 512
#define FC2_DIM 128

__global__ __launch_bounds__(256) void zero_cnt_kernel(int* cnt) {
    int i = blockIdx.x * 256 + threadIdx.x;
    if (i < N_NODES) cnt[i] = 0;
}

__global__ __launch_bounds__(256) void hist_kernel(const int* __restrict__ ei, int* __restrict__ cnt) {
    int e = blockIdx.x * 256 + threadIdx.x;
    if (e >= E_SL) return;
    int d = (e < E_IN) ? ei[E_IN + e] : (e - E_IN);
    atomicAdd(&cnt[d], 1);
}

__global__ __launch_bounds__(1024) void scan_kernel(const int* __restrict__ cnt,
                                                    int* __restrict__ rowS, int* __restrict__ rowN) {
    __shared__ int part[1024];
    int t = threadIdx.x;
    int base = t * 16;
    int local[16];
    int s = 0;
    if (base < N_NODES) {
        #pragma unroll
        for (int k = 0; k < 16; ++k) { local[k] = cnt[base + k]; s += local[k]; }
    }
    part[t] = s;
    __syncthreads();
    for (int off = 1; off < 1024; off <<= 1) {
        int v = part[t];
        int add = (t >= off) ? part[t - off] : 0;
        __syncthreads();
        part[t] = v + add;
        __syncthreads();
    }
    int excl = (t == 0) ? 0 : part[t - 1];
    if (base < N_NODES) {
        int run = excl;
        #pragma unroll
        for (int k = 0; k < 16; ++k) {
            rowS[base + k] = run;
            rowN[base + k] = run;
            run += local[k];
        }
        if (base + 16 == N_NODES) rowS[N_NODES] = run;
    }
}

__global__ __launch_bounds__(256) void scatter_kernel(const int* __restrict__ ei,
                                                      int* __restrict__ rowN, int* __restrict__ csrc) {
    int e = blockIdx.x * 256 + threadIdx.x;
    if (e >= E_SL) return;
    int s, d;
    if (e < E_IN) { s = ei[e]; d = ei[E_IN + e]; }
    else { s = e - E_IN; d = s; }
    int pos = atomicAdd(&rowN[d], 1);
    csrc[pos] = s;
}

// x0 = mean over 128 features; one wave per node
__global__ __launch_bounds__(256) void x0_kernel(const float* __restrict__ x, float* __restrict__ ms) {
    int wid = (blockIdx.x * 256 + threadIdx.x) >> 6;
    int lane = threadIdx.x & 63;
    float v = x[wid * INF + lane] + x[wid * INF + 64 + lane];
    #pragma unroll
    for (int off = 32; off > 0; off >>= 1) v += __shfl_xor(v, off, 64);
    if (lane == 0) {
        int b = wid / NODES_G, i = wid % NODES_G;
        ms[b * MS_DIM + i] = v * (1.0f / INF);
    }
}

// out1 = X@W1^T + b1 ; out2 = X@W2^T + b2 ; X:[N,128], W:[128,128]
__global__ __launch_bounds__(256) void gemm_dual_kernel(
    const float* __restrict__ X,
    const float* __restrict__ W1, const float* __restrict__ b1,
    const float* __restrict__ W2, const float* __restrict__ b2,
    float* __restrict__ out1, float* __restrict__ out2) {
    __shared__ float xs[32 * 128];
    int t = threadIdx.x;
    int row0 = blockIdx.x * 32;
    const float4* src = reinterpret_cast<const float4*>(X + (size_t)row0 * HCDIM);
    float4* dst = reinterpret_cast<float4*>(xs);
    #pragma unroll
    for (int i = 0; i < 4; ++i) dst[t + i * 256] = src[t + i * 256];
    __syncthreads();
    int col = t & 127;
    int half = t >> 7;
    const float* W = half ? W2 : W1;
    float bv = (half ? b2 : b1)[col];
    float* outp = half ? out2 : out1;
    float acc[32];
    #pragma unroll
    for (int r = 0; r < 32; ++r) acc[r] = 0.f;
    for (int k0 = 0; k0 < 128; k0 += 4) {
        float4 w4 = *reinterpret_cast<const float4*>(W + col * HCDIM + k0);
        #pragma unroll
        for (int r = 0; r < 32; ++r) {
            acc[r] += xs[r * 128 + k0] * w4.x + xs[r * 128 + k0 + 1] * w4.y
                    + xs[r * 128 + k0 + 2] * w4.z + xs[r * 128 + k0 + 3] * w4.w;
        }
    }
    #pragma unroll
    for (int r = 0; r < 32; ++r) outp[(size_t)(row0 + r) * HCDIM + col] = acc[r] + bv;
}

// Fused GATv2 per-destination-node, edge-parallel.
// 256 threads = 8 groups x 32 lanes. Lane c owns channels 4c..4c+3 (one head: c>>3).
__global__ __launch_bounds__(256) void gat_node_kernel(
    const float* __restrict__ xl, const float* __restrict__ xr,
    const int* __restrict__ rowS, const int* __restrict__ csrc,
    const float* __restrict__ att, const float* __restrict__ bias,
    const float* __restrict__ Wp, const float* __restrict__ bp,
    float* __restrict__ hout, float* __restrict__ msout) {
    int n = blockIdx.x;
    int t = threadIdx.x;
    int g = t >> 5;          // edge group 0..7
    int c = t & 31;          // lane within group
    int head = c >> 3;       // 4 channels of lane c all in this head

    __shared__ int   csrc_s[LMAX];
    __shared__ float as_[4 * LSTRIDE];   // [head][j] logits -> exp
    __shared__ float rden_s[4];
    __shared__ float part[8 * 128];      // per-group partial aggregates
    __shared__ float wred[2];

    int rs = rowS[n];
    int deg = rowS[n + 1] - rs;
    int degc = deg < LMAX ? deg : LMAX;

    if (t < degc) csrc_s[t] = csrc[rs + t];
    __syncthreads();

    float4 att4 = *reinterpret_cast<const float4*>(att + 4 * c);
    float4 xr4  = *reinterpret_cast<const float4*>(xr + (size_t)n * HCDIM + 4 * c);

    // Phase A: logits, edge-parallel; cache first 64 edges' rows in registers
    float4 cache[8];
    #pragma unroll
    for (int it = 0; it < 8; ++it) {
        int j = g + 8 * it;
        bool act = j < degc;
        int src = act ? csrc_s[j] : csrc_s[0];
        float4 v = *reinterpret_cast<const float4*>(xl + (size_t)src * HCDIM + 4 * c);
        cache[it] = v;
        float e0 = v.x + xr4.x; e0 = e0 > 0.f ? e0 : NEG_SLOPE * e0;
        float e1 = v.y + xr4.y; e1 = e1 > 0.f ? e1 : NEG_SLOPE * e1;
        float e2 = v.z + xr4.z; e2 = e2 > 0.f ? e2 : NEG_SLOPE * e2;
        float e3 = v.w + xr4.w; e3 = e3 > 0.f ? e3 : NEG_SLOPE * e3;
        float p = e0 * att4.x + e1 * att4.y + e2 * att4.z + e3 * att4.w;
        p += __shfl_xor(p, 1); p += __shfl_xor(p, 2); p += __shfl_xor(p, 4);
        if (act && (c & 7) == 0) as_[head * LSTRIDE + j] = p;
    }
    // tail edges (deg > 64): compute logits without caching
    for (int j = g + 64; j < degc; j += 8) {
        int src = csrc_s[j];
        float4 v = *reinterpret_cast<const float4*>(xl + (size_t)src * HCDIM + 4 * c);
        float e0 = v.x + xr4.x; e0 = e0 > 0.f ? e0 : NEG_SLOPE * e0;
        float e1 = v.y + xr4.y; e1 = e1 > 0.f ? e1 : NEG_SLOPE * e1;
        float e2 = v.z + xr4.z; e2 = e2 > 0.f ? e2 : NEG_SLOPE * e2;
        float e3 = v.w + xr4.w; e3 = e3 > 0.f ? e3 : NEG_SLOPE * e3;
        float p = e0 * att4.x + e1 * att4.y + e2 * att4.z + e3 * att4.w;
        p += __shfl_xor(p, 1); p += __shfl_xor(p, 2); p += __shfl_xor(p, 4);
        if ((c & 7) == 0) as_[head * LSTRIDE + j] = p;
    }
    __syncthreads();

    // Phase B: per-head softmax stats (threads 0..127: h = t>>5, s = t&31)
    if (t < 128) {
        int h = t >> 5, s = t & 31;
        float m = -1e30f;
        for (int j = s; j < degc; j += 32) m = fmaxf(m, as_[h * LSTRIDE + j]);
        #pragma unroll
        for (int o = 16; o > 0; o >>= 1) m = fmaxf(m, __shfl_xor(m, o));
        float dsum = 0.f;
        for (int j = s; j < degc; j += 32) {
            float e = __expf(as_[h * LSTRIDE + j] - m);
            as_[h * LSTRIDE + j] = e;
            dsum += e;
        }
        #pragma unroll
        for (int o = 16; o > 0; o >>= 1) dsum += __shfl_xor(dsum, o);
        if (s == 0) rden_s[h] = 1.0f / dsum;
    }
    __syncthreads();

    // Phase C: weighted aggregation, edge-parallel with register cache
    float rden = rden_s[head];
    float ax = 0.f, ay = 0.f, az = 0.f, aw = 0.f;
    #pragma unroll
    for (int it = 0; it < 8; ++it) {
        int j = g + 8 * it;
        if (j < degc) {
            float a = as_[head * LSTRIDE + j] * rden;
            ax += a * cache[it].x; ay += a * cache[it].y;
            az += a * cache[it].z; aw += a * cache[it].w;
        }
    }
    for (int j = g + 64; j < degc; j += 8) {
        int src = csrc_s[j];
        float4 v = *reinterpret_cast<const float4*>(xl + (size_t)src * HCDIM + 4 * c);
        float a = as_[head * LSTRIDE + j] * rden;
        ax += a * v.x; ay += a * v.y; az += a * v.z; aw += a * v.w;
    }
    float4* pp = reinterpret_cast<float4*>(part + g * 128 + 4 * c);
    *pp = make_float4(ax, ay, az, aw);
    __syncthreads();

    // Final: reduce 8 groups, bias+relu, store h, fused pooling
    if (t < 128) {
        float o = 0.f;
        #pragma unroll
        for (int gg = 0; gg < 8; ++gg) o += part[gg * 128 + t];
        o += bias[t];
        o = fmaxf(o, 0.f);
        hout[(size_t)n * HCDIM + t] = o;

        float p = o * Wp[t];
        #pragma unroll
        for (int off = 32; off > 0; off >>= 1) p += __shfl_xor(p, off, 64);
        if ((t & 63) == 0) wred[t >> 6] = p;
    }
    __syncthreads();
    if (t == 0) {
        int b = n / NODES_G, i = n % NODES_G;
        msout[b * MS_DIM + i] = wred[0] + wred[1] + bp[0];
    }
}

// LayerNorm in place over rows of 2000 within ms; 24 blocks
__global__ __launch_bounds__(256) void ln_kernel(float* __restrict__ ms,
                                                 const float* __restrict__ g, const float* __restrict__ bta) {
    int b = blockIdx.x / 3, st = blockIdx.x % 3;
    float* row = ms + b * MS_DIM + st * NODES_G;
    int t = threadIdx.x;
    float s = 0.f, ss = 0.f;
    for (int j = t; j < NODES_G; j += 256) { float v = row[j]; s += v; ss += v * v; }
    __shared__ float rs_[4], rss[4];
    #pragma unroll
    for (int off = 32; off > 0; off >>= 1) { s += __shfl_xor(s, off, 64); ss += __shfl_xor(ss, off, 64); }
    int w = t >> 6, lane = t & 63;
    if (lane == 0) { rs_[w] = s; rss[w] = ss; }
    __syncthreads();
    s = rs_[0] + rs_[1] + rs_[2] + rs_[3];
    ss = rss[0] + rss[1] + rss[2] + rss[3];
    float mean = s * (1.0f / NODES_G);
    float var = ss * (1.0f / NODES_G) - mean * mean;
    float rstd = rsqrtf(var + LN_EPS);
    for (int j = t; j < NODES_G; j += 256) {
        float v = row[j];
        row[j] = (v - mean) * rstd * g[j] + bta[j];
    }
}

// z[b][o] = act(sum_k in[b][k]*W[o][k] + bias[o]); one wave per o, 8 batch accs
template<int K, int OD, bool RELU>
__global__ __launch_bounds__(256) void fc_kernel(const float* __restrict__ in, const float* __restrict__ W,
                                                 const float* __restrict__ bias, float* __restrict__ z) {
    int lane = threadIdx.x & 63;
    int o = blockIdx.x * 4 + (threadIdx.x >> 6);
    float acc[8];
    #pragma unroll
    for (int b = 0; b < 8; ++b) acc[b] = 0.f;
    for (int k = lane; k < K; k += 64) {
        float wv = W[(size_t)o * K + k];
        #pragma unroll
        for (int b = 0; b < 8; ++b) acc[b] += wv * in[b * K + k];
    }
    #pragma unroll
    for (int off = 32; off > 0; off >>= 1)
        #pragma unroll
        for (int b = 0; b < 8; ++b) acc[b] += __shfl_xor(acc[b], off, 64);
    if (lane == 0) {
        float bb = bias[o];
        #pragma unroll
        for (int b = 0; b < 8; ++b) {
            float v = acc[b] + bb;
            z[b * OD + o] = RELU ? fmaxf(v, 0.f) : v;
        }
    }
}

__global__ __launch_bounds__(256) void fc3_kernel(const float* __restrict__ z2, const float* __restrict__ W,
                                                  const float* __restrict__ bias, float* __restrict__ out) {
    int t = threadIdx.x;
    int b = t >> 5, l = t & 31;
    float acc = 0.f;
    #pragma unroll
    for (int i = 0; i < 4; ++i) {
        int k = l + i * 32;
        acc += z2[b * FC2_DIM + k] * W[k];
    }
    #pragma unroll
    for (int off = 16; off > 0; off >>= 1) acc += __shfl_xor(acc, off, 32);
    if (l == 0) out[b] = acc + bias[0];
}

extern "C" void kernel_launch(void* const* d_in, const int* in_sizes, int n_in,
                              void* d_out, int out_size, void* d_ws, size_t ws_size,
                              hipStream_t stream) {
    const float* x    = (const float*)d_in[0];
    const int*   ei   = (const int*)d_in[1];
    const float* Wl1  = (const float*)d_in[2];
    const float* bl1  = (const float*)d_in[3];
    const float* Wr1  = (const float*)d_in[4];
    const float* br1  = (const float*)d_in[5];
    const float* att1 = (const float*)d_in[6];
    const float* bias1= (const float*)d_in[7];
    const float* Wl2  = (const float*)d_in[8];
    const float* bl2  = (const float*)d_in[9];
    const float* Wr2  = (const float*)d_in[10];
    const float* br2  = (const float*)d_in[11];
    const float* att2 = (const float*)d_in[12];
    const float* bias2= (const float*)d_in[13];
    const float* Wp1  = (const float*)d_in[14];
    const float* bp1  = (const float*)d_in[15];
    const float* Wp2  = (const float*)d_in[16];
    const float* bp2  = (const float*)d_in[17];
    const float* ln_g = (const float*)d_in[18];
    const float* ln_b = (const float*)d_in[19];
    const float* We1  = (const float*)d_in[20];
    const float* be1  = (const float*)d_in[21];
    const float* We2  = (const float*)d_in[22];
    const float* be2  = (const float*)d_in[23];
    const float* We3  = (const float*)d_in[24];
    const float* be3  = (const float*)d_in[25];
    float* out = (float*)d_out;

    float* ws = (float*)d_ws;
    float* xl = ws;
    float* xr = xl + (size_t)N_NODES * HCDIM;
    float* hb = xr + (size_t)N_NODES * HCDIM;
    float* ms = hb + (size_t)N_NODES * HCDIM;
    float* z1 = ms + BATCH * MS_DIM;
    float* z2 = z1 + BATCH * FC1_DIM;
    int* cnt  = (int*)(z2 + BATCH * FC2_DIM);
    int* rowS = cnt + N_NODES;
    int* rowN = rowS + (N_NODES + 1);
    int* csrc = rowN + N_NODES;

    int eb = (E_SL + 255) / 256;
    zero_cnt_kernel<<<(N_NODES + 255) / 256, 256, 0, stream>>>(cnt);
    hist_kernel<<<eb, 256, 0, stream>>>(ei, cnt);
    scan_kernel<<<1, 1024, 0, stream>>>(cnt, rowS, rowN);
    scatter_kernel<<<eb, 256, 0, stream>>>(ei, rowN, csrc);
    x0_kernel<<<N_NODES / 4, 256, 0, stream>>>(x, ms);

    gemm_dual_kernel<<<N_NODES / 32, 256, 0, stream>>>(x, Wl1, bl1, Wr1, br1, xl, xr);
    gat_node_kernel<<<N_NODES, 256, 0, stream>>>(xl, xr, rowS, csrc, att1, bias1, Wp1, bp1, hb, ms + 2000);
    gemm_dual_kernel<<<N_NODES / 32, 256, 0, stream>>>(hb, Wl2, bl2, Wr2, br2, xl, xr);
    gat_node_kernel<<<N_NODES, 256, 0, stream>>>(xl, xr, rowS, csrc, att2, bias2, Wp2, bp2, hb, ms + 4000);

    ln_kernel<<<24, 256, 0, stream>>>(ms, ln_g, ln_b);
    fc_kernel<MS_DIM, FC1_DIM, true><<<FC1_DIM / 4, 256, 0, stream>>>(ms, We1, be1, z1);
    fc_kernel<FC1_DIM, FC2_DIM, true><<<FC2_DIM / 4, 256, 0, stream>>>(z1, We2, be2, z2);
    fc3_kernel<<<1, 256, 0, stream>>>(z2, We3, be3, out);
}

// Round 8
// 401.454 us; speedup vs baseline: 2.0808x; 1.0113x over previous
//
#include <hip/hip_runtime.h>

#define N_NODES 16000
#define NODES_G 2000
#define BATCH 8
#define INF 128
#define HCDIM 128
#define E_IN 512000
#define E_SL 528000
#define CAP 96            // bucket capacity per dst (max observed deg ~58, 11-sigma margin)
#define LSTRIDE 100       // padded stride for as_ logits
#define NEG_SLOPE 0.2f
#define LN_EPS 1e-5f
#define MS_DIM 6000
#define FC1_DIM 512
#define FC2_DIM 128

// x0 = mean over 128 features (one wave per node) + zero the degree counters
__global__ __launch_bounds__(256) void x0z_kernel(const float* __restrict__ x,
                                                  float* __restrict__ ms, int* __restrict__ cnt) {
    int tid = blockIdx.x * 256 + threadIdx.x;
    if (tid < N_NODES) cnt[tid] = 0;
    int wid = tid >> 6;
    int lane = tid & 63;
    float v = x[wid * INF + lane] + x[wid * INF + 64 + lane];
    #pragma unroll
    for (int off = 32; off > 0; off >>= 1) v += __shfl_xor(v, off, 64);
    if (lane == 0) {
        int b = wid / NODES_G, i = wid % NODES_G;
        ms[b * MS_DIM + i] = v * (1.0f / INF);
    }
}

// Direct-bucket CSR: one pass, no hist/scan
__global__ __launch_bounds__(256) void scatter_kernel(const int* __restrict__ ei,
                                                      int* __restrict__ cnt, ushort* __restrict__ csrc) {
    int e = blockIdx.x * 256 + threadIdx.x;
    if (e >= E_SL) return;
    int s, d;
    if (e < E_IN) { s = ei[e]; d = ei[E_IN + e]; }
    else { s = e - E_IN; d = s; }
    int pos = atomicAdd(&cnt[d], 1);
    if (pos < CAP) csrc[d * CAP + pos] = (ushort)s;
}

// out1 = X@W1^T + b1 ; out2 = X@W2^T + b2 ; X:[N,128], W:[128,128]
__global__ __launch_bounds__(256) void gemm_dual_kernel(
    const float* __restrict__ X,
    const float* __restrict__ W1, const float* __restrict__ b1,
    const float* __restrict__ W2, const float* __restrict__ b2,
    float* __restrict__ out1, float* __restrict__ out2) {
    __shared__ float xs[32 * 128];
    int t = threadIdx.x;
    int row0 = blockIdx.x * 32;
    const float4* src = reinterpret_cast<const float4*>(X + (size_t)row0 * HCDIM);
    float4* dst = reinterpret_cast<float4*>(xs);
    #pragma unroll
    for (int i = 0; i < 4; ++i) dst[t + i * 256] = src[t + i * 256];
    __syncthreads();
    int col = t & 127;
    int half = t >> 7;
    const float* W = half ? W2 : W1;
    float bv = (half ? b2 : b1)[col];
    float* outp = half ? out2 : out1;
    float acc[32];
    #pragma unroll
    for (int r = 0; r < 32; ++r) acc[r] = 0.f;
    for (int k0 = 0; k0 < 128; k0 += 4) {
        float4 w4 = *reinterpret_cast<const float4*>(W + col * HCDIM + k0);
        #pragma unroll
        for (int r = 0; r < 32; ++r) {
            acc[r] += xs[r * 128 + k0] * w4.x + xs[r * 128 + k0 + 1] * w4.y
                    + xs[r * 128 + k0 + 2] * w4.z + xs[r * 128 + k0 + 3] * w4.w;
        }
    }
    #pragma unroll
    for (int r = 0; r < 32; ++r) outp[(size_t)(row0 + r) * HCDIM + col] = acc[r] + bv;
}

// Fused GATv2 per-destination-node, edge-parallel with inactive-slot skipping.
// 256 threads = 8 groups x 32 lanes. Lane c owns channels 4c..4c+3 (head c>>3).
__global__ __launch_bounds__(256) void gat_node_kernel(
    const float* __restrict__ xl, const float* __restrict__ xr,
    const int* __restrict__ cnt, const ushort* __restrict__ csrc,
    const float* __restrict__ att, const float* __restrict__ bias,
    const float* __restrict__ Wp, const float* __restrict__ bp,
    float* __restrict__ hout, float* __restrict__ msout) {
    int n = blockIdx.x;
    int t = threadIdx.x;
    int g = t >> 5;
    int c = t & 31;
    int head = c >> 3;

    __shared__ int   csrc_s[CAP];
    __shared__ float as_[4 * LSTRIDE];
    __shared__ float rden_s[4];
    __shared__ float part[8 * 128];
    __shared__ float wred[2];

    int deg = cnt[n];
    int degc = deg < CAP ? deg : CAP;

    if (t < degc) csrc_s[t] = (int)csrc[n * CAP + t];
    __syncthreads();

    float4 att4 = *reinterpret_cast<const float4*>(att + 4 * c);
    float4 xr4  = *reinterpret_cast<const float4*>(xr + (size_t)n * HCDIM + 4 * c);

    // Phase A: logits, edge-parallel; cache first 64 edges' rows in registers.
    // Guarded: skip load+math for inactive slots (branch is near-wave-uniform).
    float4 cache[8];
    #pragma unroll
    for (int it = 0; it < 8; ++it) {
        int j = g + 8 * it;
        if (j < degc) {
            int src = csrc_s[j];
            float4 v = *reinterpret_cast<const float4*>(xl + (size_t)src * HCDIM + 4 * c);
            cache[it] = v;
            float e0 = v.x + xr4.x; e0 = e0 > 0.f ? e0 : NEG_SLOPE * e0;
            float e1 = v.y + xr4.y; e1 = e1 > 0.f ? e1 : NEG_SLOPE * e1;
            float e2 = v.z + xr4.z; e2 = e2 > 0.f ? e2 : NEG_SLOPE * e2;
            float e3 = v.w + xr4.w; e3 = e3 > 0.f ? e3 : NEG_SLOPE * e3;
            float p = e0 * att4.x + e1 * att4.y + e2 * att4.z + e3 * att4.w;
            p += __shfl_xor(p, 1); p += __shfl_xor(p, 2); p += __shfl_xor(p, 4);
            if ((c & 7) == 0) as_[head * LSTRIDE + j] = p;
        }
    }
    for (int j = g + 64; j < degc; j += 8) {
        int src = csrc_s[j];
        float4 v = *reinterpret_cast<const float4*>(xl + (size_t)src * HCDIM + 4 * c);
        float e0 = v.x + xr4.x; e0 = e0 > 0.f ? e0 : NEG_SLOPE * e0;
        float e1 = v.y + xr4.y; e1 = e1 > 0.f ? e1 : NEG_SLOPE * e1;
        float e2 = v.z + xr4.z; e2 = e2 > 0.f ? e2 : NEG_SLOPE * e2;
        float e3 = v.w + xr4.w; e3 = e3 > 0.f ? e3 : NEG_SLOPE * e3;
        float p = e0 * att4.x + e1 * att4.y + e2 * att4.z + e3 * att4.w;
        p += __shfl_xor(p, 1); p += __shfl_xor(p, 2); p += __shfl_xor(p, 4);
        if ((c & 7) == 0) as_[head * LSTRIDE + j] = p;
    }
    __syncthreads();

    // Phase B: per-head softmax stats (threads 0..127: h = t>>5, s = t&31)
    if (t < 128) {
        int h = t >> 5, s = t & 31;
        float m = -1e30f;
        for (int j = s; j < degc; j += 32) m = fmaxf(m, as_[h * LSTRIDE + j]);
        #pragma unroll
        for (int o = 16; o > 0; o >>= 1) m = fmaxf(m, __shfl_xor(m, o));
        float dsum = 0.f;
        for (int j = s; j < degc; j += 32) {
            float e = __expf(as_[h * LSTRIDE + j] - m);
            as_[h * LSTRIDE + j] = e;
            dsum += e;
        }
        #pragma unroll
        for (int o = 16; o > 0; o >>= 1) dsum += __shfl_xor(dsum, o);
        if (s == 0) rden_s[h] = 1.0f / dsum;
    }
    __syncthreads();

    // Phase C: weighted aggregation (guarded, register cache)
    float rden = rden_s[head];
    float ax = 0.f, ay = 0.f, az = 0.f, aw = 0.f;
    #pragma unroll
    for (int it = 0; it < 8; ++it) {
        int j = g + 8 * it;
        if (j < degc) {
            float a = as_[head * LSTRIDE + j] * rden;
            ax += a * cache[it].x; ay += a * cache[it].y;
            az += a * cache[it].z; aw += a * cache[it].w;
        }
    }
    for (int j = g + 64; j < degc; j += 8) {
        int src = csrc_s[j];
        float4 v = *reinterpret_cast<const float4*>(xl + (size_t)src * HCDIM + 4 * c);
        float a = as_[head * LSTRIDE + j] * rden;
        ax += a * v.x; ay += a * v.y; az += a * v.z; aw += a * v.w;
    }
    float4* pp = reinterpret_cast<float4*>(part + g * 128 + 4 * c);
    *pp = make_float4(ax, ay, az, aw);
    __syncthreads();

    if (t < 128) {
        float o = 0.f;
        #pragma unroll
        for (int gg = 0; gg < 8; ++gg) o += part[gg * 128 + t];
        o += bias[t];
        o = fmaxf(o, 0.f);
        hout[(size_t)n * HCDIM + t] = o;

        float p = o * Wp[t];
        #pragma unroll
        for (int off = 32; off > 0; off >>= 1) p += __shfl_xor(p, off, 64);
        if ((t & 63) == 0) wred[t >> 6] = p;
    }
    __syncthreads();
    if (t == 0) {
        int b = n / NODES_G, i = n % NODES_G;
        msout[b * MS_DIM + i] = wred[0] + wred[1] + bp[0];
    }
}

// LayerNorm in place over rows of 2000 within ms; 24 blocks
__global__ __launch_bounds__(256) void ln_kernel(float* __restrict__ ms,
                                                 const float* __restrict__ g, const float* __restrict__ bta) {
    int b = blockIdx.x / 3, st = blockIdx.x % 3;
    float* row = ms + b * MS_DIM + st * NODES_G;
    int t = threadIdx.x;
    float s = 0.f, ss = 0.f;
    for (int j = t; j < NODES_G; j += 256) { float v = row[j]; s += v; ss += v * v; }
    __shared__ float rs_[4], rss[4];
    #pragma unroll
    for (int off = 32; off > 0; off >>= 1) { s += __shfl_xor(s, off, 64); ss += __shfl_xor(ss, off, 64); }
    int w = t >> 6, lane = t & 63;
    if (lane == 0) { rs_[w] = s; rss[w] = ss; }
    __syncthreads();
    s = rs_[0] + rs_[1] + rs_[2] + rs_[3];
    ss = rss[0] + rss[1] + rss[2] + rss[3];
    float mean = s * (1.0f / NODES_G);
    float var = ss * (1.0f / NODES_G) - mean * mean;
    float rstd = rsqrtf(var + LN_EPS);
    for (int j = t; j < NODES_G; j += 256) {
        float v = row[j];
        row[j] = (v - mean) * rstd * g[j] + bta[j];
    }
}

// fc1: z[b][o] = relu(sum_k in[b][k]*W[o][k] + bias[o]); one wave per o, 8 batch accs
template<int K, int OD>
__global__ __launch_bounds__(256) void fc_kernel(const float* __restrict__ in, const float* __restrict__ W,
                                                 const float* __restrict__ bias, float* __restrict__ z) {
    int lane = threadIdx.x & 63;
    int o = blockIdx.x * 4 + (threadIdx.x >> 6);
    float acc[8];
    #pragma unroll
    for (int b = 0; b < 8; ++b) acc[b] = 0.f;
    for (int k = lane; k < K; k += 64) {
        float wv = W[(size_t)o * K + k];
        #pragma unroll
        for (int b = 0; b < 8; ++b) acc[b] += wv * in[b * K + k];
    }
    #pragma unroll
    for (int off = 32; off > 0; off >>= 1)
        #pragma unroll
        for (int b = 0; b < 8; ++b) acc[b] += __shfl_xor(acc[b], off, 64);
    if (lane == 0) {
        float bb = bias[o];
        #pragma unroll
        for (int b = 0; b < 8; ++b) z[b * OD + o] = fmaxf(acc[b] + bb, 0.f);
    }
}

// Fused fc2 (relu) + fc3: single block, z1 and z2 staged in LDS
__global__ __launch_bounds__(256) void fc23_kernel(const float* __restrict__ z1,
                                                   const float* __restrict__ We2, const float* __restrict__ be2,
                                                   const float* __restrict__ We3, const float* __restrict__ be3,
                                                   float* __restrict__ out) {
    __shared__ float z1s[BATCH * FC1_DIM];   // 16 KB
    __shared__ float z2s[BATCH * FC2_DIM];   // 4 KB
    int t = threadIdx.x;
    float4* z1s4 = reinterpret_cast<float4*>(z1s);
    const float4* z14 = reinterpret_cast<const float4*>(z1);
    #pragma unroll
    for (int i = 0; i < 4; ++i) z1s4[t + 256 * i] = z14[t + 256 * i];
    __syncthreads();
    #pragma unroll
    for (int u = 0; u < 4; ++u) {
        int idx = t + 256 * u;          // idx = b*128 + o
        int b = idx >> 7, o = idx & 127;
        const float4* w4 = reinterpret_cast<const float4*>(We2 + (size_t)o * FC1_DIM);
        const float4* zz = reinterpret_cast<const float4*>(z1s + b * FC1_DIM);
        float acc = 0.f;
        for (int k = 0; k < FC1_DIM / 4; ++k) {
            float4 w = w4[k], z = zz[k];
            acc += w.x * z.x + w.y * z.y + w.z * z.z + w.w * z.w;
        }
        z2s[idx] = fmaxf(acc + be2[o], 0.f);
    }
    __syncthreads();
    int b = t >> 5, l = t & 31;
    float acc = z2s[b * 128 + l] * We3[l] + z2s[b * 128 + l + 32] * We3[l + 32]
              + z2s[b * 128 + l + 64] * We3[l + 64] + z2s[b * 128 + l + 96] * We3[l + 96];
    #pragma unroll
    for (int off = 16; off > 0; off >>= 1) acc += __shfl_xor(acc, off, 32);
    if (l == 0) out[b] = acc + be3[0];
}

extern "C" void kernel_launch(void* const* d_in, const int* in_sizes, int n_in,
                              void* d_out, int out_size, void* d_ws, size_t ws_size,
                              hipStream_t stream) {
    const float* x    = (const float*)d_in[0];
    const int*   ei   = (const int*)d_in[1];
    const float* Wl1  = (const float*)d_in[2];
    const float* bl1  = (const float*)d_in[3];
    const float* Wr1  = (const float*)d_in[4];
    const float* br1  = (const float*)d_in[5];
    const float* att1 = (const float*)d_in[6];
    const float* bias1= (const float*)d_in[7];
    const float* Wl2  = (const float*)d_in[8];
    const float* bl2  = (const float*)d_in[9];
    const float* Wr2  = (const float*)d_in[10];
    const float* br2  = (const float*)d_in[11];
    const float* att2 = (const float*)d_in[12];
    const float* bias2= (const float*)d_in[13];
    const float* Wp1  = (const float*)d_in[14];
    const float* bp1  = (const float*)d_in[15];
    const float* Wp2  = (const float*)d_in[16];
    const float* bp2  = (const float*)d_in[17];
    const float* ln_g = (const float*)d_in[18];
    const float* ln_b = (const float*)d_in[19];
    const float* We1  = (const float*)d_in[20];
    const float* be1  = (const float*)d_in[21];
    const float* We2  = (const float*)d_in[22];
    const float* be2  = (const float*)d_in[23];
    const float* We3  = (const float*)d_in[24];
    const float* be3  = (const float*)d_in[25];
    float* out = (float*)d_out;

    float* ws = (float*)d_ws;
    float* xl = ws;
    float* xr = xl + (size_t)N_NODES * HCDIM;
    float* hb = xr + (size_t)N_NODES * HCDIM;
    float* ms = hb + (size_t)N_NODES * HCDIM;
    float* z1 = ms + BATCH * MS_DIM;
    int* cnt  = (int*)(z1 + BATCH * FC1_DIM);
    ushort* csrc = (ushort*)(cnt + N_NODES);

    int eb = (E_SL + 255) / 256;
    x0z_kernel<<<N_NODES / 4, 256, 0, stream>>>(x, ms, cnt);
    scatter_kernel<<<eb, 256, 0, stream>>>(ei, cnt, csrc);

    gemm_dual_kernel<<<N_NODES / 32, 256, 0, stream>>>(x, Wl1, bl1, Wr1, br1, xl, xr);
    gat_node_kernel<<<N_NODES, 256, 0, stream>>>(xl, xr, cnt, csrc, att1, bias1, Wp1, bp1, hb, ms + 2000);
    gemm_dual_kernel<<<N_NODES / 32, 256, 0, stream>>>(hb, Wl2, bl2, Wr2, br2, xl, xr);
    gat_node_kernel<<<N_NODES, 256, 0, stream>>>(xl, xr, cnt, csrc, att2, bias2, Wp2, bp2, hb, ms + 4000);

    ln_kernel<<<24, 256, 0, stream>>>(ms, ln_g, ln_b);
    fc_kernel<MS_DIM, FC1_DIM><<<FC1_DIM / 4, 256, 0, stream>>>(ms, We1, be1, z1);
    fc23_kernel<<<1, 256, 0, stream>>>(z1, We2, be2, We3, be3, out);
}

// Round 9
// 348.343 us; speedup vs baseline: 2.3981x; 1.1525x over previous
//
#include <hip/hip_runtime.h>

#define N_NODES 16000
#define NODES_G 2000
#define BATCH 8
#define INF 128
#define HCDIM 128
#define E_IN 512000
#define E_SL 528000
#define CAP 96            // bucket capacity per dst (max observed deg ~58, 11-sigma margin)
#define LSTRIDE 100       // padded stride for as_ logits
#define NEG_SLOPE 0.2f
#define LN_EPS 1e-5f
#define MS_DIM 6000
#define FC1_DIM 512
#define FC2_DIM 128

// x0 = mean over 128 features (one wave per node) + zero the degree counters
__global__ __launch_bounds__(256) void x0z_kernel(const float* __restrict__ x,
                                                  float* __restrict__ ms, int* __restrict__ cnt) {
    int tid = blockIdx.x * 256 + threadIdx.x;
    if (tid < N_NODES) cnt[tid] = 0;
    int wid = tid >> 6;
    int lane = tid & 63;
    float v = x[wid * INF + lane] + x[wid * INF + 64 + lane];
    #pragma unroll
    for (int off = 32; off > 0; off >>= 1) v += __shfl_xor(v, off, 64);
    if (lane == 0) {
        int b = wid / NODES_G, i = wid % NODES_G;
        ms[b * MS_DIM + i] = v * (1.0f / INF);
    }
}

// Direct-bucket CSR: one pass, no hist/scan
__global__ __launch_bounds__(256) void scatter_kernel(const int* __restrict__ ei,
                                                      int* __restrict__ cnt, ushort* __restrict__ csrc) {
    int e = blockIdx.x * 256 + threadIdx.x;
    if (e >= E_SL) return;
    int s, d;
    if (e < E_IN) { s = ei[e]; d = ei[E_IN + e]; }
    else { s = e - E_IN; d = s; }
    int pos = atomicAdd(&cnt[d], 1);
    if (pos < CAP) csrc[d * CAP + pos] = (ushort)s;
}

// out1 = X@W1^T + b1 ; out2 = X@W2^T + b2 ; X:[N,128], W:[128,128]
__global__ __launch_bounds__(256) void gemm_dual_kernel(
    const float* __restrict__ X,
    const float* __restrict__ W1, const float* __restrict__ b1,
    const float* __restrict__ W2, const float* __restrict__ b2,
    float* __restrict__ out1, float* __restrict__ out2) {
    __shared__ float xs[32 * 128];
    int t = threadIdx.x;
    int row0 = blockIdx.x * 32;
    const float4* src = reinterpret_cast<const float4*>(X + (size_t)row0 * HCDIM);
    float4* dst = reinterpret_cast<float4*>(xs);
    #pragma unroll
    for (int i = 0; i < 4; ++i) dst[t + i * 256] = src[t + i * 256];
    __syncthreads();
    int col = t & 127;
    int half = t >> 7;
    const float* W = half ? W2 : W1;
    float bv = (half ? b2 : b1)[col];
    float* outp = half ? out2 : out1;
    float acc[32];
    #pragma unroll
    for (int r = 0; r < 32; ++r) acc[r] = 0.f;
    for (int k0 = 0; k0 < 128; k0 += 4) {
        float4 w4 = *reinterpret_cast<const float4*>(W + col * HCDIM + k0);
        #pragma unroll
        for (int r = 0; r < 32; ++r) {
            acc[r] += xs[r * 128 + k0] * w4.x + xs[r * 128 + k0 + 1] * w4.y
                    + xs[r * 128 + k0 + 2] * w4.z + xs[r * 128 + k0 + 3] * w4.w;
        }
    }
    #pragma unroll
    for (int r = 0; r < 32; ++r) outp[(size_t)(row0 + r) * HCDIM + col] = acc[r] + bv;
}

// Fused GATv2 per-destination-node, edge-parallel with inactive-slot skipping.
// 256 threads = 8 groups x 32 lanes. Lane c owns channels 4c..4c+3 (head c>>3).
__global__ __launch_bounds__(256) void gat_node_kernel(
    const float* __restrict__ xl, const float* __restrict__ xr,
    const int* __restrict__ cnt, const ushort* __restrict__ csrc,
    const float* __restrict__ att, const float* __restrict__ bias,
    const float* __restrict__ Wp, const float* __restrict__ bp,
    float* __restrict__ hout, float* __restrict__ msout) {
    int n = blockIdx.x;
    int t = threadIdx.x;
    int g = t >> 5;
    int c = t & 31;
    int head = c >> 3;

    __shared__ int   csrc_s[CAP];
    __shared__ float as_[4 * LSTRIDE];
    __shared__ float rden_s[4];
    __shared__ float part[8 * 128];
    __shared__ float wred[2];

    int deg = cnt[n];
    int degc = deg < CAP ? deg : CAP;

    if (t < degc) csrc_s[t] = (int)csrc[n * CAP + t];
    __syncthreads();

    float4 att4 = *reinterpret_cast<const float4*>(att + 4 * c);
    float4 xr4  = *reinterpret_cast<const float4*>(xr + (size_t)n * HCDIM + 4 * c);

    // Phase A: logits, edge-parallel; cache first 64 edges' rows in registers.
    // Guarded: skip load+math for inactive slots (branch is near-wave-uniform).
    float4 cache[8];
    #pragma unroll
    for (int it = 0; it < 8; ++it) {
        int j = g + 8 * it;
        if (j < degc) {
            int src = csrc_s[j];
            float4 v = *reinterpret_cast<const float4*>(xl + (size_t)src * HCDIM + 4 * c);
            cache[it] = v;
            float e0 = v.x + xr4.x; e0 = e0 > 0.f ? e0 : NEG_SLOPE * e0;
            float e1 = v.y + xr4.y; e1 = e1 > 0.f ? e1 : NEG_SLOPE * e1;
            float e2 = v.z + xr4.z; e2 = e2 > 0.f ? e2 : NEG_SLOPE * e2;
            float e3 = v.w + xr4.w; e3 = e3 > 0.f ? e3 : NEG_SLOPE * e3;
            float p = e0 * att4.x + e1 * att4.y + e2 * att4.z + e3 * att4.w;
            p += __shfl_xor(p, 1); p += __shfl_xor(p, 2); p += __shfl_xor(p, 4);
            if ((c & 7) == 0) as_[head * LSTRIDE + j] = p;
        }
    }
    for (int j = g + 64; j < degc; j += 8) {
        int src = csrc_s[j];
        float4 v = *reinterpret_cast<const float4*>(xl + (size_t)src * HCDIM + 4 * c);
        float e0 = v.x + xr4.x; e0 = e0 > 0.f ? e0 : NEG_SLOPE * e0;
        float e1 = v.y + xr4.y; e1 = e1 > 0.f ? e1 : NEG_SLOPE * e1;
        float e2 = v.z + xr4.z; e2 = e2 > 0.f ? e2 : NEG_SLOPE * e2;
        float e3 = v.w + xr4.w; e3 = e3 > 0.f ? e3 : NEG_SLOPE * e3;
        float p = e0 * att4.x + e1 * att4.y + e2 * att4.z + e3 * att4.w;
        p += __shfl_xor(p, 1); p += __shfl_xor(p, 2); p += __shfl_xor(p, 4);
        if ((c & 7) == 0) as_[head * LSTRIDE + j] = p;
    }
    __syncthreads();

    // Phase B: per-head softmax stats (threads 0..127: h = t>>5, s = t&31)
    if (t < 128) {
        int h = t >> 5, s = t & 31;
        float m = -1e30f;
        for (int j = s; j < degc; j += 32) m = fmaxf(m, as_[h * LSTRIDE + j]);
        #pragma unroll
        for (int o = 16; o > 0; o >>= 1) m = fmaxf(m, __shfl_xor(m, o));
        float dsum = 0.f;
        for (int j = s; j < degc; j += 32) {
            float e = __expf(as_[h * LSTRIDE + j] - m);
            as_[h * LSTRIDE + j] = e;
            dsum += e;
        }
        #pragma unroll
        for (int o = 16; o > 0; o >>= 1) dsum += __shfl_xor(dsum, o);
        if (s == 0) rden_s[h] = 1.0f / dsum;
    }
    __syncthreads();

    // Phase C: weighted aggregation (guarded, register cache)
    float rden = rden_s[head];
    float ax = 0.f, ay = 0.f, az = 0.f, aw = 0.f;
    #pragma unroll
    for (int it = 0; it < 8; ++it) {
        int j = g + 8 * it;
        if (j < degc) {
            float a = as_[head * LSTRIDE + j] * rden;
            ax += a * cache[it].x; ay += a * cache[it].y;
            az += a * cache[it].z; aw += a * cache[it].w;
        }
    }
    for (int j = g + 64; j < degc; j += 8) {
        int src = csrc_s[j];
        float4 v = *reinterpret_cast<const float4*>(xl + (size_t)src * HCDIM + 4 * c);
        float a = as_[head * LSTRIDE + j] * rden;
        ax += a * v.x; ay += a * v.y; az += a * v.z; aw += a * v.w;
    }
    float4* pp = reinterpret_cast<float4*>(part + g * 128 + 4 * c);
    *pp = make_float4(ax, ay, az, aw);
    __syncthreads();

    if (t < 128) {
        float o = 0.f;
        #pragma unroll
        for (int gg = 0; gg < 8; ++gg) o += part[gg * 128 + t];
        o += bias[t];
        o = fmaxf(o, 0.f);
        hout[(size_t)n * HCDIM + t] = o;

        float p = o * Wp[t];
        #pragma unroll
        for (int off = 32; off > 0; off >>= 1) p += __shfl_xor(p, off, 64);
        if ((t & 63) == 0) wred[t >> 6] = p;
    }
    __syncthreads();
    if (t == 0) {
        int b = n / NODES_G, i = n % NODES_G;
        msout[b * MS_DIM + i] = wred[0] + wred[1] + bp[0];
    }
}

// LayerNorm in place over rows of 2000 within ms; 24 blocks
__global__ __launch_bounds__(256) void ln_kernel(float* __restrict__ ms,
                                                 const float* __restrict__ g, const float* __restrict__ bta) {
    int b = blockIdx.x / 3, st = blockIdx.x % 3;
    float* row = ms + b * MS_DIM + st * NODES_G;
    int t = threadIdx.x;
    float s = 0.f, ss = 0.f;
    for (int j = t; j < NODES_G; j += 256) { float v = row[j]; s += v; ss += v * v; }
    __shared__ float rs_[4], rss[4];
    #pragma unroll
    for (int off = 32; off > 0; off >>= 1) { s += __shfl_xor(s, off, 64); ss += __shfl_xor(ss, off, 64); }
    int w = t >> 6, lane = t & 63;
    if (lane == 0) { rs_[w] = s; rss[w] = ss; }
    __syncthreads();
    s = rs_[0] + rs_[1] + rs_[2] + rs_[3];
    ss = rss[0] + rss[1] + rss[2] + rss[3];
    float mean = s * (1.0f / NODES_G);
    float var = ss * (1.0f / NODES_G) - mean * mean;
    float rstd = rsqrtf(var + LN_EPS);
    for (int j = t; j < NODES_G; j += 256) {
        float v = row[j];
        row[j] = (v - mean) * rstd * g[j] + bta[j];
    }
}

// fc: z[b][o] = act(sum_k in[b][k]*W[o][k] + bias[o]); one wave per o, 8 batch accs
template<int K, int OD, bool RELU>
__global__ __launch_bounds__(256) void fc_kernel(const float* __restrict__ in, const float* __restrict__ W,
                                                 const float* __restrict__ bias, float* __restrict__ z) {
    int lane = threadIdx.x & 63;
    int o = blockIdx.x * 4 + (threadIdx.x >> 6);
    float acc[8];
    #pragma unroll
    for (int b = 0; b < 8; ++b) acc[b] = 0.f;
    for (int k = lane; k < K; k += 64) {
        float wv = W[(size_t)o * K + k];
        #pragma unroll
        for (int b = 0; b < 8; ++b) acc[b] += wv * in[b * K + k];
    }
    #pragma unroll
    for (int off = 32; off > 0; off >>= 1)
        #pragma unroll
        for (int b = 0; b < 8; ++b) acc[b] += __shfl_xor(acc[b], off, 64);
    if (lane == 0) {
        float bb = bias[o];
        #pragma unroll
        for (int b = 0; b < 8; ++b) {
            float v = acc[b] + bb;
            z[b * OD + o] = RELU ? fmaxf(v, 0.f) : v;
        }
    }
}

__global__ __launch_bounds__(256) void fc3_kernel(const float* __restrict__ z2, const float* __restrict__ W,
                                                  const float* __restrict__ bias, float* __restrict__ out) {
    int t = threadIdx.x;
    int b = t >> 5, l = t & 31;
    float acc = 0.f;
    #pragma unroll
    for (int i = 0; i < 4; ++i) {
        int k = l + i * 32;
        acc += z2[b * FC2_DIM + k] * W[k];
    }
    #pragma unroll
    for (int off = 16; off > 0; off >>= 1) acc += __shfl_xor(acc, off, 32);
    if (l == 0) out[b] = acc + bias[0];
}

extern "C" void kernel_launch(void* const* d_in, const int* in_sizes, int n_in,
                              void* d_out, int out_size, void* d_ws, size_t ws_size,
                              hipStream_t stream) {
    const float* x    = (const float*)d_in[0];
    const int*   ei   = (const int*)d_in[1];
    const float* Wl1  = (const float*)d_in[2];
    const float* bl1  = (const float*)d_in[3];
    const float* Wr1  = (const float*)d_in[4];
    const float* br1  = (const float*)d_in[5];
    const float* att1 = (const float*)d_in[6];
    const float* bias1= (const float*)d_in[7];
    const float* Wl2  = (const float*)d_in[8];
    const float* bl2  = (const float*)d_in[9];
    const float* Wr2  = (const float*)d_in[10];
    const float* br2  = (const float*)d_in[11];
    const float* att2 = (const float*)d_in[12];
    const float* bias2= (const float*)d_in[13];
    const float* Wp1  = (const float*)d_in[14];
    const float* bp1  = (const float*)d_in[15];
    const float* Wp2  = (const float*)d_in[16];
    const float* bp2  = (const float*)d_in[17];
    const float* ln_g = (const float*)d_in[18];
    const float* ln_b = (const float*)d_in[19];
    const float* We1  = (const float*)d_in[20];
    const float* be1  = (const float*)d_in[21];
    const float* We2  = (const float*)d_in[22];
    const float* be2  = (const float*)d_in[23];
    const float* We3  = (const float*)d_in[24];
    const float* be3  = (const float*)d_in[25];
    float* out = (float*)d_out;

    float* ws = (float*)d_ws;
    float* xl = ws;
    float* xr = xl + (size_t)N_NODES * HCDIM;
    float* hb = xr + (size_t)N_NODES * HCDIM;
    float* ms = hb + (size_t)N_NODES * HCDIM;
    float* z1 = ms + BATCH * MS_DIM;
    float* z2 = z1 + BATCH * FC1_DIM;
    int* cnt  = (int*)(z2 + BATCH * FC2_DIM);
    ushort* csrc = (ushort*)(cnt + N_NODES);

    int eb = (E_SL + 255) / 256;
    x0z_kernel<<<N_NODES / 4, 256, 0, stream>>>(x, ms, cnt);
    scatter_kernel<<<eb, 256, 0, stream>>>(ei, cnt, csrc);

    gemm_dual_kernel<<<N_NODES / 32, 256, 0, stream>>>(x, Wl1, bl1, Wr1, br1, xl, xr);
    gat_node_kernel<<<N_NODES, 256, 0, stream>>>(xl, xr, cnt, csrc, att1, bias1, Wp1, bp1, hb, ms + 2000);
    gemm_dual_kernel<<<N_NODES / 32, 256, 0, stream>>>(hb, Wl2, bl2, Wr2, br2, xl, xr);
    gat_node_kernel<<<N_NODES, 256, 0, stream>>>(xl, xr, cnt, csrc, att2, bias2, Wp2, bp2, hb, ms + 4000);

    ln_kernel<<<24, 256, 0, stream>>>(ms, ln_g, ln_b);
    fc_kernel<MS_DIM, FC1_DIM, true><<<FC1_DIM / 4, 256, 0, stream>>>(ms, We1, be1, z1);
    fc_kernel<FC1_DIM, FC2_DIM, true><<<FC2_DIM / 4, 256, 0, stream>>>(z1, We2, be2, z2);
    fc3_kernel<<<1, 256, 0, stream>>>(z2, We3, be3, out);
}

// Round 10
// 317.408 us; speedup vs baseline: 2.6318x; 1.0975x over previous
//
#include <hip/hip_runtime.h>

#define N_NODES 16000
#define NODES_G 2000
#define BATCH 8
#define INF 128
#define HCDIM 128
#define E_IN 512000
#define E_SL 528000
#define CAP 96            // bucket capacity per dst (max observed deg ~58, 11-sigma margin)
#define LSTRIDE 100       // padded stride for as_ logits
#define NEG_SLOPE 0.2f
#define LN_EPS 1e-5f
#define MS_DIM 6000
#define FC1_DIM 512
#define FC2_DIM 128

// x0 = mean over 128 features (one wave per node) + zero the degree counters
__global__ __launch_bounds__(256) void x0z_kernel(const float* __restrict__ x,
                                                  float* __restrict__ ms, int* __restrict__ cnt) {
    int tid = blockIdx.x * 256 + threadIdx.x;
    if (tid < N_NODES) cnt[tid] = 0;
    int wid = tid >> 6;
    int lane = tid & 63;
    float v = x[wid * INF + lane] + x[wid * INF + 64 + lane];
    #pragma unroll
    for (int off = 32; off > 0; off >>= 1) v += __shfl_xor(v, off, 64);
    if (lane == 0) {
        int b = wid / NODES_G, i = wid % NODES_G;
        ms[b * MS_DIM + i] = v * (1.0f / INF);
    }
}

// Direct-bucket CSR: one pass, no hist/scan
__global__ __launch_bounds__(256) void scatter_kernel(const int* __restrict__ ei,
                                                      int* __restrict__ cnt, ushort* __restrict__ csrc) {
    int e = blockIdx.x * 256 + threadIdx.x;
    if (e >= E_SL) return;
    int s, d;
    if (e < E_IN) { s = ei[e]; d = ei[E_IN + e]; }
    else { s = e - E_IN; d = s; }
    int pos = atomicAdd(&cnt[d], 1);
    if (pos < CAP) csrc[d * CAP + pos] = (ushort)s;
}

// out1 = X@W1^T + b1 ; out2 = X@W2^T + b2 ; X:[N,128], W:[128,128]
__global__ __launch_bounds__(256) void gemm_dual_kernel(
    const float* __restrict__ X,
    const float* __restrict__ W1, const float* __restrict__ b1,
    const float* __restrict__ W2, const float* __restrict__ b2,
    float* __restrict__ out1, float* __restrict__ out2) {
    __shared__ float xs[32 * 128];
    int t = threadIdx.x;
    int row0 = blockIdx.x * 32;
    const float4* src = reinterpret_cast<const float4*>(X + (size_t)row0 * HCDIM);
    float4* dst = reinterpret_cast<float4*>(xs);
    #pragma unroll
    for (int i = 0; i < 4; ++i) dst[t + i * 256] = src[t + i * 256];
    __syncthreads();
    int col = t & 127;
    int half = t >> 7;
    const float* W = half ? W2 : W1;
    float bv = (half ? b2 : b1)[col];
    float* outp = half ? out2 : out1;
    float acc[32];
    #pragma unroll
    for (int r = 0; r < 32; ++r) acc[r] = 0.f;
    for (int k0 = 0; k0 < 128; k0 += 4) {
        float4 w4 = *reinterpret_cast<const float4*>(W + col * HCDIM + k0);
        #pragma unroll
        for (int r = 0; r < 32; ++r) {
            acc[r] += xs[r * 128 + k0] * w4.x + xs[r * 128 + k0 + 1] * w4.y
                    + xs[r * 128 + k0 + 2] * w4.z + xs[r * 128 + k0 + 3] * w4.w;
        }
    }
    #pragma unroll
    for (int r = 0; r < 32; ++r) outp[(size_t)(row0 + r) * HCDIM + col] = acc[r] + bv;
}

// Fused GATv2 per-destination-node, edge-parallel with inactive-slot skipping.
// 256 threads = 8 groups x 32 lanes. Lane c owns channels 4c..4c+3 (head c>>3).
__global__ __launch_bounds__(256) void gat_node_kernel(
    const float* __restrict__ xl, const float* __restrict__ xr,
    const int* __restrict__ cnt, const ushort* __restrict__ csrc,
    const float* __restrict__ att, const float* __restrict__ bias,
    const float* __restrict__ Wp, const float* __restrict__ bp,
    float* __restrict__ hout, float* __restrict__ msout) {
    int n = blockIdx.x;
    int t = threadIdx.x;
    int g = t >> 5;
    int c = t & 31;
    int head = c >> 3;

    __shared__ int   csrc_s[CAP];
    __shared__ float as_[4 * LSTRIDE];
    __shared__ float rden_s[4];
    __shared__ float part[8 * 128];
    __shared__ float wred[2];

    int deg = cnt[n];
    int degc = deg < CAP ? deg : CAP;

    if (t < degc) csrc_s[t] = (int)csrc[n * CAP + t];
    __syncthreads();

    float4 att4 = *reinterpret_cast<const float4*>(att + 4 * c);
    float4 xr4  = *reinterpret_cast<const float4*>(xr + (size_t)n * HCDIM + 4 * c);

    // Phase A: logits, edge-parallel; cache first 64 edges' rows in registers.
    float4 cache[8];
    #pragma unroll
    for (int it = 0; it < 8; ++it) {
        int j = g + 8 * it;
        if (j < degc) {
            int src = csrc_s[j];
            float4 v = *reinterpret_cast<const float4*>(xl + (size_t)src * HCDIM + 4 * c);
            cache[it] = v;
            float e0 = v.x + xr4.x; e0 = e0 > 0.f ? e0 : NEG_SLOPE * e0;
            float e1 = v.y + xr4.y; e1 = e1 > 0.f ? e1 : NEG_SLOPE * e1;
            float e2 = v.z + xr4.z; e2 = e2 > 0.f ? e2 : NEG_SLOPE * e2;
            float e3 = v.w + xr4.w; e3 = e3 > 0.f ? e3 : NEG_SLOPE * e3;
            float p = e0 * att4.x + e1 * att4.y + e2 * att4.z + e3 * att4.w;
            p += __shfl_xor(p, 1); p += __shfl_xor(p, 2); p += __shfl_xor(p, 4);
            if ((c & 7) == 0) as_[head * LSTRIDE + j] = p;
        }
    }
    for (int j = g + 64; j < degc; j += 8) {
        int src = csrc_s[j];
        float4 v = *reinterpret_cast<const float4*>(xl + (size_t)src * HCDIM + 4 * c);
        float e0 = v.x + xr4.x; e0 = e0 > 0.f ? e0 : NEG_SLOPE * e0;
        float e1 = v.y + xr4.y; e1 = e1 > 0.f ? e1 : NEG_SLOPE * e1;
        float e2 = v.z + xr4.z; e2 = e2 > 0.f ? e2 : NEG_SLOPE * e2;
        float e3 = v.w + xr4.w; e3 = e3 > 0.f ? e3 : NEG_SLOPE * e3;
        float p = e0 * att4.x + e1 * att4.y + e2 * att4.z + e3 * att4.w;
        p += __shfl_xor(p, 1); p += __shfl_xor(p, 2); p += __shfl_xor(p, 4);
        if ((c & 7) == 0) as_[head * LSTRIDE + j] = p;
    }
    __syncthreads();

    // Phase B: per-head softmax stats (threads 0..127: h = t>>5, s = t&31)
    if (t < 128) {
        int h = t >> 5, s = t & 31;
        float m = -1e30f;
        for (int j = s; j < degc; j += 32) m = fmaxf(m, as_[h * LSTRIDE + j]);
        #pragma unroll
        for (int o = 16; o > 0; o >>= 1) m = fmaxf(m, __shfl_xor(m, o));
        float dsum = 0.f;
        for (int j = s; j < degc; j += 32) {
            float e = __expf(as_[h * LSTRIDE + j] - m);
            as_[h * LSTRIDE + j] = e;
            dsum += e;
        }
        #pragma unroll
        for (int o = 16; o > 0; o >>= 1) dsum += __shfl_xor(dsum, o);
        if (s == 0) rden_s[h] = 1.0f / dsum;
    }
    __syncthreads();

    // Phase C: weighted aggregation (guarded, register cache)
    float rden = rden_s[head];
    float ax = 0.f, ay = 0.f, az = 0.f, aw = 0.f;
    #pragma unroll
    for (int it = 0; it < 8; ++it) {
        int j = g + 8 * it;
        if (j < degc) {
            float a = as_[head * LSTRIDE + j] * rden;
            ax += a * cache[it].x; ay += a * cache[it].y;
            az += a * cache[it].z; aw += a * cache[it].w;
        }
    }
    for (int j = g + 64; j < degc; j += 8) {
        int src = csrc_s[j];
        float4 v = *reinterpret_cast<const float4*>(xl + (size_t)src * HCDIM + 4 * c);
        float a = as_[head * LSTRIDE + j] * rden;
        ax += a * v.x; ay += a * v.y; az += a * v.z; aw += a * v.w;
    }
    float4* pp = reinterpret_cast<float4*>(part + g * 128 + 4 * c);
    *pp = make_float4(ax, ay, az, aw);
    __syncthreads();

    if (t < 128) {
        float o = 0.f;
        #pragma unroll
        for (int gg = 0; gg < 8; ++gg) o += part[gg * 128 + t];
        o += bias[t];
        o = fmaxf(o, 0.f);
        hout[(size_t)n * HCDIM + t] = o;

        float p = o * Wp[t];
        #pragma unroll
        for (int off = 32; off > 0; off >>= 1) p += __shfl_xor(p, off, 64);
        if ((t & 63) == 0) wred[t >> 6] = p;
    }
    __syncthreads();
    if (t == 0) {
        int b = n / NODES_G, i = n % NODES_G;
        msout[b * MS_DIM + i] = wred[0] + wred[1] + bp[0];
    }
}

// LayerNorm in place over rows of 2000 within ms; 24 blocks
__global__ __launch_bounds__(256) void ln_kernel(float* __restrict__ ms,
                                                 const float* __restrict__ g, const float* __restrict__ bta) {
    int b = blockIdx.x / 3, st = blockIdx.x % 3;
    float* row = ms + b * MS_DIM + st * NODES_G;
    int t = threadIdx.x;
    float s = 0.f, ss = 0.f;
    for (int j = t; j < NODES_G; j += 256) { float v = row[j]; s += v; ss += v * v; }
    __shared__ float rs_[4], rss[4];
    #pragma unroll
    for (int off = 32; off > 0; off >>= 1) { s += __shfl_xor(s, off, 64); ss += __shfl_xor(ss, off, 64); }
    int w = t >> 6, lane = t & 63;
    if (lane == 0) { rs_[w] = s; rss[w] = ss; }
    __syncthreads();
    s = rs_[0] + rs_[1] + rs_[2] + rs_[3];
    ss = rss[0] + rss[1] + rss[2] + rss[3];
    float mean = s * (1.0f / NODES_G);
    float var = ss * (1.0f / NODES_G) - mean * mean;
    float rstd = rsqrtf(var + LN_EPS);
    for (int j = t; j < NODES_G; j += 256) {
        float v = row[j];
        row[j] = (v - mean) * rstd * g[j] + bta[j];
    }
}

// Block-per-output FC: grid = OD blocks, 256 threads stride K on the weight row.
// 8 batch accumulators in registers; wave shuffle + LDS reduce; thread b<8 stores z[b][o].
template<int K, int OD, bool RELU>
__global__ __launch_bounds__(256) void fcb_kernel(const float* __restrict__ in, const float* __restrict__ W,
                                                  const float* __restrict__ bias, float* __restrict__ z) {
    int o = blockIdx.x;
    int t = threadIdx.x;
    const float* wrow = W + (size_t)o * K;
    float acc[8];
    #pragma unroll
    for (int b = 0; b < 8; ++b) acc[b] = 0.f;
    for (int k = t; k < K; k += 256) {
        float wv = wrow[k];
        #pragma unroll
        for (int b = 0; b < 8; ++b) acc[b] += wv * in[b * K + k];
    }
    #pragma unroll
    for (int off = 32; off > 0; off >>= 1)
        #pragma unroll
        for (int b = 0; b < 8; ++b) acc[b] += __shfl_xor(acc[b], off, 64);
    __shared__ float red[4][8];
    int w = t >> 6, lane = t & 63;
    if (lane == 0) {
        #pragma unroll
        for (int b = 0; b < 8; ++b) red[w][b] = acc[b];
    }
    __syncthreads();
    if (t < 8) {
        float v = red[0][t] + red[1][t] + red[2][t] + red[3][t] + bias[o];
        z[t * OD + o] = RELU ? fmaxf(v, 0.f) : v;
    }
}

__global__ __launch_bounds__(256) void fc3_kernel(const float* __restrict__ z2, const float* __restrict__ W,
                                                  const float* __restrict__ bias, float* __restrict__ out) {
    int t = threadIdx.x;
    int b = t >> 5, l = t & 31;
    float acc = 0.f;
    #pragma unroll
    for (int i = 0; i < 4; ++i) {
        int k = l + i * 32;
        acc += z2[b * FC2_DIM + k] * W[k];
    }
    #pragma unroll
    for (int off = 16; off > 0; off >>= 1) acc += __shfl_xor(acc, off, 32);
    if (l == 0) out[b] = acc + bias[0];
}

extern "C" void kernel_launch(void* const* d_in, const int* in_sizes, int n_in,
                              void* d_out, int out_size, void* d_ws, size_t ws_size,
                              hipStream_t stream) {
    const float* x    = (const float*)d_in[0];
    const int*   ei   = (const int*)d_in[1];
    const float* Wl1  = (const float*)d_in[2];
    const float* bl1  = (const float*)d_in[3];
    const float* Wr1  = (const float*)d_in[4];
    const float* br1  = (const float*)d_in[5];
    const float* att1 = (const float*)d_in[6];
    const float* bias1= (const float*)d_in[7];
    const float* Wl2  = (const float*)d_in[8];
    const float* bl2  = (const float*)d_in[9];
    const float* Wr2  = (const float*)d_in[10];
    const float* br2  = (const float*)d_in[11];
    const float* att2 = (const float*)d_in[12];
    const float* bias2= (const float*)d_in[13];
    const float* Wp1  = (const float*)d_in[14];
    const float* bp1  = (const float*)d_in[15];
    const float* Wp2  = (const float*)d_in[16];
    const float* bp2  = (const float*)d_in[17];
    const float* ln_g = (const float*)d_in[18];
    const float* ln_b = (const float*)d_in[19];
    const float* We1  = (const float*)d_in[20];
    const float* be1  = (const float*)d_in[21];
    const float* We2  = (const float*)d_in[22];
    const float* be2  = (const float*)d_in[23];
    const float* We3  = (const float*)d_in[24];
    const float* be3  = (const float*)d_in[25];
    float* out = (float*)d_out;

    float* ws = (float*)d_ws;
    float* xl = ws;
    float* xr = xl + (size_t)N_NODES * HCDIM;
    float* hb = xr + (size_t)N_NODES * HCDIM;
    float* ms = hb + (size_t)N_NODES * HCDIM;
    float* z1 = ms + BATCH * MS_DIM;
    float* z2 = z1 + BATCH * FC1_DIM;
    int* cnt  = (int*)(z2 + BATCH * FC2_DIM);
    ushort* csrc = (ushort*)(cnt + N_NODES);

    int eb = (E_SL + 255) / 256;
    x0z_kernel<<<N_NODES / 4, 256, 0, stream>>>(x, ms, cnt);
    scatter_kernel<<<eb, 256, 0, stream>>>(ei, cnt, csrc);

    gemm_dual_kernel<<<N_NODES / 32, 256, 0, stream>>>(x, Wl1, bl1, Wr1, br1, xl, xr);
    gat_node_kernel<<<N_NODES, 256, 0, stream>>>(xl, xr, cnt, csrc, att1, bias1, Wp1, bp1, hb, ms + 2000);
    gemm_dual_kernel<<<N_NODES / 32, 256, 0, stream>>>(hb, Wl2, bl2, Wr2, br2, xl, xr);
    gat_node_kernel<<<N_NODES, 256, 0, stream>>>(xl, xr, cnt, csrc, att2, bias2, Wp2, bp2, hb, ms + 4000);

    ln_kernel<<<24, 256, 0, stream>>>(ms, ln_g, ln_b);
    fcb_kernel<MS_DIM, FC1_DIM, true><<<FC1_DIM, 256, 0, stream>>>(ms, We1, be1, z1);
    fcb_kernel<FC1_DIM, FC2_DIM, true><<<FC2_DIM, 256, 0, stream>>>(z1, We2, be2, z2);
    fc3_kernel<<<1, 256, 0, stream>>>(z2, We3, be3, out);
}